// Round 16
// baseline (78.171 us; speedup 1.0000x reference)
//
#include <hip/hip_runtime.h>

// CondInst dynamic mask head, fused (R16 = R15 + TH=50 + vectorized Phase-B).
// mask_feats (2,8,200,200) f32, params (128,169) f32 x2, locs (128,2) f32,
// im_inds/fpn_levels int32, stride scalar int (=8).
// Output: 2 x (128,1,400,400) f32 concat flat.

#define BLOCK 256
#define Hh 200
#define Ww 200
#define NP 169
#define TH 50      // output rows per tile
#define MAXR 27    // max source rows per tile (factor=2)
#define OW 400
#define OH 400
#define PSTR 192   // per-head packed-param stride (floats)

typedef float f32x4 __attribute__((ext_vector_type(4)));
typedef float f32x2 __attribute__((ext_vector_type(2)));
typedef _Float16 f16x4 __attribute__((ext_vector_type(4)));

__device__ __forceinline__ f32x2 splat2(float v) { f32x2 r; r.x = v; r.y = v; return r; }
__device__ __forceinline__ f32x4 splat4(float v) { f32x4 r; r.x = v; r.y = v; r.z = v; r.w = v; return r; }
__device__ __forceinline__ f32x2 pkfma(f32x2 a, f32x2 b, f32x2 c) {
    return __builtin_elementwise_fma(a, b, c);
}

// packed per-head layout (PSTR floats, all reads 16B-aligned b128):
//   L1 row o at o*12: [w0..w9, bias, pad] -> [0,96)
//   L2 w rows (8 x 8) -> [96,160) ; L2 biases -> [160,168)
//   L3 w -> [168,176) ; L3 bias -> [176]
__device__ __forceinline__ int park_dst(int k) {
    if (k < 80)  return (k / 10) * 12 + (k % 10);   // L1 w
    if (k < 144) return 96 + (k - 80);              // L2 w
    if (k < 152) return 168 + (k - 144);            // L3 w
    if (k < 160) return (k - 152) * 12 + 10;        // L1 b
    if (k < 168) return 160 + (k - 160);            // L2 b
    return 176;                                      // L3 b
}

// 3-layer MLP on 4 px (xa = px{0,1}, xb = px{2,3}); weights at P (LDS).
__device__ __forceinline__ void mlp4(const float* __restrict__ P,
    const f32x2 (&xa)[10], const f32x2 (&xb)[10], f32x2& oa_, f32x2& ob_)
{
    const f32x2 zero = splat2(0.0f);

    f32x2 h1a[8], h1b[8];
    #pragma unroll
    for (int o = 0; o < 8; o++) {
        const f32x4 wa = *(const f32x4*)(P + o * 12);       // w0..w3
        const f32x4 wb = *(const f32x4*)(P + o * 12 + 4);   // w4..w7
        const f32x4 wc = *(const f32x4*)(P + o * 12 + 8);   // w8, w9, bias, pad
        f32x2 aa = splat2(wc.z);
        f32x2 ab = aa;
        aa = pkfma(splat2(wa.x), xa[0], aa); ab = pkfma(splat2(wa.x), xb[0], ab);
        aa = pkfma(splat2(wa.y), xa[1], aa); ab = pkfma(splat2(wa.y), xb[1], ab);
        aa = pkfma(splat2(wa.z), xa[2], aa); ab = pkfma(splat2(wa.z), xb[2], ab);
        aa = pkfma(splat2(wa.w), xa[3], aa); ab = pkfma(splat2(wa.w), xb[3], ab);
        aa = pkfma(splat2(wb.x), xa[4], aa); ab = pkfma(splat2(wb.x), xb[4], ab);
        aa = pkfma(splat2(wb.y), xa[5], aa); ab = pkfma(splat2(wb.y), xb[5], ab);
        aa = pkfma(splat2(wb.z), xa[6], aa); ab = pkfma(splat2(wb.z), xb[6], ab);
        aa = pkfma(splat2(wb.w), xa[7], aa); ab = pkfma(splat2(wb.w), xb[7], ab);
        aa = pkfma(splat2(wc.x), xa[8], aa); ab = pkfma(splat2(wc.x), xb[8], ab);
        aa = pkfma(splat2(wc.y), xa[9], aa); ab = pkfma(splat2(wc.y), xb[9], ab);
        h1a[o] = __builtin_elementwise_max(aa, zero);
        h1b[o] = __builtin_elementwise_max(ab, zero);
    }

    const f32x4 blo = *(const f32x4*)(P + 160);
    const f32x4 bhi = *(const f32x4*)(P + 164);
    const float b1v[8] = {blo.x, blo.y, blo.z, blo.w, bhi.x, bhi.y, bhi.z, bhi.w};

    f32x2 h2a[8], h2b[8];
    #pragma unroll
    for (int o = 0; o < 8; o++) {
        const f32x4 wa = *(const f32x4*)(P + 96 + o * 8);
        const f32x4 wb = *(const f32x4*)(P + 96 + o * 8 + 4);
        f32x2 aa = splat2(b1v[o]);
        f32x2 ab = aa;
        aa = pkfma(splat2(wa.x), h1a[0], aa); ab = pkfma(splat2(wa.x), h1b[0], ab);
        aa = pkfma(splat2(wa.y), h1a[1], aa); ab = pkfma(splat2(wa.y), h1b[1], ab);
        aa = pkfma(splat2(wa.z), h1a[2], aa); ab = pkfma(splat2(wa.z), h1b[2], ab);
        aa = pkfma(splat2(wa.w), h1a[3], aa); ab = pkfma(splat2(wa.w), h1b[3], ab);
        aa = pkfma(splat2(wb.x), h1a[4], aa); ab = pkfma(splat2(wb.x), h1b[4], ab);
        aa = pkfma(splat2(wb.y), h1a[5], aa); ab = pkfma(splat2(wb.y), h1b[5], ab);
        aa = pkfma(splat2(wb.z), h1a[6], aa); ab = pkfma(splat2(wb.z), h1b[6], ab);
        aa = pkfma(splat2(wb.w), h1a[7], aa); ab = pkfma(splat2(wb.w), h1b[7], ab);
        h2a[o] = __builtin_elementwise_max(aa, zero);
        h2b[o] = __builtin_elementwise_max(ab, zero);
    }

    const f32x4 wa = *(const f32x4*)(P + 168);
    const f32x4 wb = *(const f32x4*)(P + 172);
    const float b2 = P[176];
    f32x2 aa = splat2(b2);
    f32x2 ab = aa;
    aa = pkfma(splat2(wa.x), h2a[0], aa); ab = pkfma(splat2(wa.x), h2b[0], ab);
    aa = pkfma(splat2(wa.y), h2a[1], aa); ab = pkfma(splat2(wa.y), h2b[1], ab);
    aa = pkfma(splat2(wa.z), h2a[2], aa); ab = pkfma(splat2(wa.z), h2b[2], ab);
    aa = pkfma(splat2(wa.w), h2a[3], aa); ab = pkfma(splat2(wa.w), h2b[3], ab);
    aa = pkfma(splat2(wb.x), h2a[4], aa); ab = pkfma(splat2(wb.x), h2b[4], ab);
    aa = pkfma(splat2(wb.y), h2a[5], aa); ab = pkfma(splat2(wb.y), h2b[5], ab);
    aa = pkfma(splat2(wb.z), h2a[6], aa); ab = pkfma(splat2(wb.z), h2b[6], ab);
    aa = pkfma(splat2(wb.w), h2a[7], aa); ab = pkfma(splat2(wb.w), h2b[7], ab);
    oa_ = aa; ob_ = ab;
}

__global__ __launch_bounds__(BLOCK, 4) void dmh_fused(
    const float* __restrict__ mask_feats,
    const float* __restrict__ mparams,
    const float* __restrict__ bparams,
    const float* __restrict__ ilocs,
    const int*   __restrict__ im_inds,
    const int*   __restrict__ fpn_levels,
    const int*   __restrict__ stride_p,
    float* __restrict__ out,
    int n_inst)
{
    __shared__ __align__(16) float s_par[2 * PSTR];        // 1.5 KB
    __shared__ __align__(16) _Float16 s_m[2][MAXR][Ww];    // 21.6 KB

    const int tid  = threadIdx.x;
    const int tile = blockIdx.x;   // 0..7
    const int inst = blockIdx.y;

    for (int j = tid; j < 2 * NP; j += BLOCK) {
        const int head = (j < NP) ? 0 : 1;
        const int k = j - head * NP;
        const float v = head ? bparams[inst * NP + k] : mparams[inst * NP + k];
        s_par[head * PSTR + park_dst(k)] = v;
    }

    const int   s    = stride_p[0];       // 8
    const int   half = s >> 1;
    const int   im   = im_inds[inst];
    const int   lvl  = fpn_levels[inst];
    const float inv_soi = 1.0f / (float)(64 << lvl);  // SOI = 64*2^lvl exactly
    const float ixl = ilocs[inst * 2 + 0];
    const float iyl = ilocs[inst * 2 + 1];

    const int i0 = tile * TH;
    const int r_begin = ((i0 > 0) ? (i0 - 1) : 0) >> 1;
    int r_end = ((i0 + TH - 2) >> 1) + 1;
    if (r_end > Hh - 1) r_end = Hh - 1;
    const int nrows = r_end - r_begin + 1;   // 26 or 27

    __syncthreads();

    // ---------- Phase A: head MLP at 200-res into LDS (pk-f32, 4 px/chunk) ----------
    const int npx = nrows * Ww;                 // multiple of 4
    const float* fbase = mask_feats + (size_t)im * 8 * Hh * Ww;

    for (int g = tid * 4; g < npx; g += BLOCK * 4) {
        // prevent hoisting of LDS weight loads across iterations (VGPR blowup)
        asm volatile("" ::: "memory");

        const int lr = g / Ww;
        const int c  = g - lr * Ww;             // multiple of 4
        const int r  = r_begin + lr;

        // xa = px {0,1}, xb = px {2,3} for the 10 input channels
        f32x2 xa[10], xb[10];
        {
            const float ry   = (iyl - (float)(r * s + half)) * inv_soi;
            const float step = -(float)s * inv_soi;
            const float cx0  = (ixl - (float)(c * s + half)) * inv_soi;
            xa[0].x = cx0;            xa[0].y = cx0 + step;
            xb[0].x = cx0 + 2*step;   xb[0].y = cx0 + 3*step;
            xa[1] = splat2(ry);       xb[1] = xa[1];
            const float* fp = fbase + r * Ww + c;
            #pragma unroll
            for (int ch = 0; ch < 8; ch++) {
                const f32x4 f = *(const f32x4*)(fp + ch * (Hh * Ww));
                xa[2 + ch].x = f.x; xa[2 + ch].y = f.y;
                xb[2 + ch].x = f.z; xb[2 + ch].y = f.w;
            }
        }

        #pragma unroll 1
        for (int head = 0; head < 2; head++) {
            f32x2 oa, ob;
            mlp4(s_par + head * PSTR, xa, xb, oa, ob);
            f16x4 res;
            res.x = (_Float16)oa.x; res.y = (_Float16)oa.y;
            res.z = (_Float16)ob.x; res.w = (_Float16)ob.y;
            *(f16x4*)(&s_m[head][lr][c]) = res;
        }
    }

    __syncthreads();

    // ---------- Phase B: aligned_bilinear x2 + sigmoid (8 px/task, vectorized) ----------
    // One task = 8 output px from one aligned 8B f16x4 read per source row
    // + 1 guarded scalar left-neighbor. sigmoid = rcp(1 + exp2(C*v)) with
    // C = -log2(e) folded into the y-interp (x-interps are linear).
    float* out0 = out + (size_t)inst * (OH * OW) + (size_t)i0 * OW;
    float* out1 = out0 + (size_t)n_inst * (OH * OW);

    const float C = -1.44269504f;     // -log2(e)
    const int NU = OW / 8;            // 50 groups per output row
    const int ntaskb = TH * NU;       // 2500
    for (int t = tid; t < ntaskb; t += BLOCK) {
        const int row = t / NU;
        const int u   = t - row * NU;
        const int i   = i0 + row;
        const int ip  = (i > 0) ? (i - 1) : 0;
        const int y0  = ip >> 1;
        const float wy = (ip & 1) ? 0.5f : 0.0f;
        const int lr0 = y0 - r_begin;
        const int r1c = (y0 + 1 <= Hh - 1) ? (y0 + 1) : (Hh - 1);
        const int lr1 = r1c - r_begin;

        #pragma unroll
        for (int head = 0; head < 2; head++) {
            const f16x4 A0h = *(const f16x4*)(&s_m[head][lr0][4 * u]);
            const f16x4 A1h = *(const f16x4*)(&s_m[head][lr1][4 * u]);
            float p0 = 0.0f, p1 = 0.0f;
            if (u > 0) {
                p0 = (float)s_m[head][lr0][4 * u - 1];
                p1 = (float)s_m[head][lr1][4 * u - 1];
            }
            const f32x4 a0 = __builtin_convertvector(A0h, f32x4);
            const f32x4 a1 = __builtin_convertvector(A1h, f32x4);

            // y-interp, pre-scaled by C (vector pk ops)
            const f32x4 B4 = (a0 + (a1 - a0) * splat4(wy)) * splat4(C);
            const float PB = (u > 0) ? (p0 + (p1 - p0) * wy) * C : B4.x;

            // shifted = {PB, B0, B1, B2}; evens = 0.5*(shifted + B4)
            f32x4 sh;
            sh.x = PB; sh.y = B4.x; sh.z = B4.y; sh.w = B4.z;
            const f32x4 ev = (sh + B4) * splat4(0.5f);

            // interleave: e = {ev0, B0, ev1, B1, ev2, B2, ev3, B3}
            f32x4 lo, hi;
            lo.x = __builtin_amdgcn_rcpf(1.0f + __builtin_amdgcn_exp2f(ev.x));
            lo.y = __builtin_amdgcn_rcpf(1.0f + __builtin_amdgcn_exp2f(B4.x));
            lo.z = __builtin_amdgcn_rcpf(1.0f + __builtin_amdgcn_exp2f(ev.y));
            lo.w = __builtin_amdgcn_rcpf(1.0f + __builtin_amdgcn_exp2f(B4.y));
            hi.x = __builtin_amdgcn_rcpf(1.0f + __builtin_amdgcn_exp2f(ev.z));
            hi.y = __builtin_amdgcn_rcpf(1.0f + __builtin_amdgcn_exp2f(B4.z));
            hi.z = __builtin_amdgcn_rcpf(1.0f + __builtin_amdgcn_exp2f(ev.w));
            hi.w = __builtin_amdgcn_rcpf(1.0f + __builtin_amdgcn_exp2f(B4.w));

            float* dst = (head ? out1 : out0) + row * OW + 8 * u;
            __builtin_nontemporal_store(lo, (f32x4*)dst);
            __builtin_nontemporal_store(hi, (f32x4*)(dst + 4));
        }
    }
}

extern "C" void kernel_launch(void* const* d_in, const int* in_sizes, int n_in,
                              void* d_out, int out_size, void* d_ws, size_t ws_size,
                              hipStream_t stream) {
    const float* mask_feats = (const float*)d_in[0];
    const float* mparams    = (const float*)d_in[1];
    const float* bparams    = (const float*)d_in[2];
    const float* ilocs      = (const float*)d_in[3];
    const int*   im_inds    = (const int*)d_in[4];
    const int*   fpn_levels = (const int*)d_in[5];
    const int*   stride_p   = (const int*)d_in[6];
    float* out = (float*)d_out;

    const int n_inst = in_sizes[1] / NP;      // 128
    dim3 grid(OH / TH, n_inst);               // (8, 128)
    dim3 block(BLOCK);
    hipLaunchKernelGGL(dmh_fused, grid, block, 0, stream,
                       mask_feats, mparams, bparams, ilocs,
                       im_inds, fpn_levels, stride_p, out, n_inst);
}

// Round 17
// 65.245 us; speedup vs baseline: 1.1981x; 1.1981x over previous
//
#include <hip/hip_runtime.h>

// CondInst dynamic mask head, fused — R17 = exact revert to R11 (best: 65.3 µs).
// mask_feats (2,8,200,200) f32, params (128,169) f32 x2, locs (128,2) f32,
// im_inds/fpn_levels int32, stride scalar int (=8).
// Output: 2 x (128,1,400,400) f32 concat flat.
//
// Proven recipe: weights packed in LDS (s_par), pk-fma 4px/chunk Phase A
// (VGPR~60, anti-hoist clobber), f16 mask tile, TH=25 (grid 2048),
// Phase B 8px/task + fast sigmoid rcp(1+exp2(C*v)), nt f32x4 stores.
// Falsified alternatives (R6-R16): SGPR weights, 2-kernel split, dup-weight
// pairs, straight-line Phase A, b128-only packing, TH=40/50, 16px Phase B,
// occupancy boosts. Only instruction-count cuts moved the needle.

#define BLOCK 256
#define Hh 200
#define Ww 200
#define NP 169
#define TH 25      // output rows per tile
#define MAXR 14    // max head rows needed per tile (factor=2)
#define OW 400
#define OH 400

typedef float f32x4 __attribute__((ext_vector_type(4)));
typedef float f32x2 __attribute__((ext_vector_type(2)));
typedef _Float16 f16x4 __attribute__((ext_vector_type(4)));

__device__ __forceinline__ f32x2 splat2(float v) { f32x2 r; r.x = v; r.y = v; return r; }
__device__ __forceinline__ f32x2 pkfma(f32x2 a, f32x2 b, f32x2 c) {
    return __builtin_elementwise_fma(a, b, c);
}

__global__ __launch_bounds__(BLOCK, 4) void dmh_fused(
    const float* __restrict__ mask_feats,
    const float* __restrict__ mparams,
    const float* __restrict__ bparams,
    const float* __restrict__ ilocs,
    const int*   __restrict__ im_inds,
    const int*   __restrict__ fpn_levels,
    const int*   __restrict__ stride_p,
    float* __restrict__ out,
    int n_inst)
{
    // params repacked per head into 192 floats (16B-aligned rows):
    //   w0 rows (8 x 10) stride 12 -> [0,96)
    //   w1 rows (8 x 8)            -> [96,160)
    //   w2 (8)                     -> [160,168)
    //   b0 -> [168,176), b1 -> [176,184), b2 -> [184]
    __shared__ __align__(16) float s_par[2 * 192];
    __shared__ __align__(16) _Float16 s_m[2][MAXR][Ww];   // 11.2 KB

    const int tid  = threadIdx.x;
    const int tile = blockIdx.x;   // 0..15
    const int inst = blockIdx.y;

    for (int j = tid; j < 2 * NP; j += BLOCK) {
        const int head = (j < NP) ? 0 : 1;
        const int k = j - head * NP;
        const float v = head ? bparams[inst * NP + k] : mparams[inst * NP + k];
        int dst;
        if      (k < 80)  dst = (k / 10) * 12 + (k % 10);
        else if (k < 144) dst = 96 + (k - 80);
        else if (k < 152) dst = 160 + (k - 144);
        else if (k < 160) dst = 168 + (k - 152);
        else if (k < 168) dst = 176 + (k - 160);
        else              dst = 184;
        s_par[head * 192 + dst] = v;
    }

    const int   s    = stride_p[0];       // 8
    const int   half = s >> 1;
    const int   im   = im_inds[inst];
    const int   lvl  = fpn_levels[inst];
    const float inv_soi = 1.0f / (float)(64 << lvl);  // SOI = 64*2^lvl exactly
    const float ixl = ilocs[inst * 2 + 0];
    const float iyl = ilocs[inst * 2 + 1];

    const int i0 = tile * TH;
    const int r_begin = ((i0 > 0) ? (i0 - 1) : 0) >> 1;
    int r_end = ((i0 + TH - 2) >> 1) + 1;
    if (r_end > Hh - 1) r_end = Hh - 1;
    const int nrows = r_end - r_begin + 1;   // 13 or 14

    __syncthreads();

    // ---------- Phase A: head MLP at 200-res into LDS (pk-f32, 4 px/chunk) ----------
    const int npx = nrows * Ww;                 // multiple of 4
    const float* fbase = mask_feats + (size_t)im * 8 * Hh * Ww;

    for (int g = tid * 4; g < npx; g += BLOCK * 4) {
        // prevent hoisting of LDS weight loads across iterations (VGPR blowup)
        asm volatile("" ::: "memory");

        const int lr = g / Ww;
        const int c  = g - lr * Ww;             // multiple of 4
        const int r  = r_begin + lr;

        // xa = px {0,1}, xb = px {2,3} for the 10 input channels
        f32x2 xa[10], xb[10];
        {
            const float ry   = (iyl - (float)(r * s + half)) * inv_soi;
            const float step = -(float)s * inv_soi;
            const float cx0  = (ixl - (float)(c * s + half)) * inv_soi;
            xa[0].x = cx0;            xa[0].y = cx0 + step;
            xb[0].x = cx0 + 2*step;   xb[0].y = cx0 + 3*step;
            xa[1] = splat2(ry);       xb[1] = xa[1];
            const float* fp = fbase + r * Ww + c;
            #pragma unroll
            for (int ch = 0; ch < 8; ch++) {
                const f32x4 f = *(const f32x4*)(fp + ch * (Hh * Ww));
                xa[2 + ch].x = f.x; xa[2 + ch].y = f.y;
                xb[2 + ch].x = f.z; xb[2 + ch].y = f.w;
            }
        }

        #pragma unroll 1
        for (int head = 0; head < 2; head++) {
            const float* P = s_par + head * 192;
            const f32x2 zero = splat2(0.0f);

            f32x2 h1a[8], h1b[8];
            #pragma unroll
            for (int o = 0; o < 8; o++) {
                const f32x4 wa = *(const f32x4*)(P + o * 12);
                const f32x4 wb = *(const f32x4*)(P + o * 12 + 4);
                const float w8 = P[o * 12 + 8];
                const float w9 = P[o * 12 + 9];
                f32x2 aa = splat2(P[168 + o]);
                f32x2 ab = aa;
                aa = pkfma(splat2(wa.x), xa[0], aa); ab = pkfma(splat2(wa.x), xb[0], ab);
                aa = pkfma(splat2(wa.y), xa[1], aa); ab = pkfma(splat2(wa.y), xb[1], ab);
                aa = pkfma(splat2(wa.z), xa[2], aa); ab = pkfma(splat2(wa.z), xb[2], ab);
                aa = pkfma(splat2(wa.w), xa[3], aa); ab = pkfma(splat2(wa.w), xb[3], ab);
                aa = pkfma(splat2(wb.x), xa[4], aa); ab = pkfma(splat2(wb.x), xb[4], ab);
                aa = pkfma(splat2(wb.y), xa[5], aa); ab = pkfma(splat2(wb.y), xb[5], ab);
                aa = pkfma(splat2(wb.z), xa[6], aa); ab = pkfma(splat2(wb.z), xb[6], ab);
                aa = pkfma(splat2(wb.w), xa[7], aa); ab = pkfma(splat2(wb.w), xb[7], ab);
                aa = pkfma(splat2(w8),   xa[8], aa); ab = pkfma(splat2(w8),   xb[8], ab);
                aa = pkfma(splat2(w9),   xa[9], aa); ab = pkfma(splat2(w9),   xb[9], ab);
                h1a[o] = __builtin_elementwise_max(aa, zero);
                h1b[o] = __builtin_elementwise_max(ab, zero);
            }

            f32x2 h2a[8], h2b[8];
            #pragma unroll
            for (int o = 0; o < 8; o++) {
                const f32x4 wa = *(const f32x4*)(P + 96 + o * 8);
                const f32x4 wb = *(const f32x4*)(P + 96 + o * 8 + 4);
                f32x2 aa = splat2(P[176 + o]);
                f32x2 ab = aa;
                aa = pkfma(splat2(wa.x), h1a[0], aa); ab = pkfma(splat2(wa.x), h1b[0], ab);
                aa = pkfma(splat2(wa.y), h1a[1], aa); ab = pkfma(splat2(wa.y), h1b[1], ab);
                aa = pkfma(splat2(wa.z), h1a[2], aa); ab = pkfma(splat2(wa.z), h1b[2], ab);
                aa = pkfma(splat2(wa.w), h1a[3], aa); ab = pkfma(splat2(wa.w), h1b[3], ab);
                aa = pkfma(splat2(wb.x), h1a[4], aa); ab = pkfma(splat2(wb.x), h1b[4], ab);
                aa = pkfma(splat2(wb.y), h1a[5], aa); ab = pkfma(splat2(wb.y), h1b[5], ab);
                aa = pkfma(splat2(wb.z), h1a[6], aa); ab = pkfma(splat2(wb.z), h1b[6], ab);
                aa = pkfma(splat2(wb.w), h1a[7], aa); ab = pkfma(splat2(wb.w), h1b[7], ab);
                h2a[o] = __builtin_elementwise_max(aa, zero);
                h2b[o] = __builtin_elementwise_max(ab, zero);
            }

            const f32x4 wa = *(const f32x4*)(P + 160);
            const f32x4 wb = *(const f32x4*)(P + 164);
            f32x2 aa = splat2(P[184]);
            f32x2 ab = aa;
            aa = pkfma(splat2(wa.x), h2a[0], aa); ab = pkfma(splat2(wa.x), h2b[0], ab);
            aa = pkfma(splat2(wa.y), h2a[1], aa); ab = pkfma(splat2(wa.y), h2b[1], ab);
            aa = pkfma(splat2(wa.z), h2a[2], aa); ab = pkfma(splat2(wa.z), h2b[2], ab);
            aa = pkfma(splat2(wa.w), h2a[3], aa); ab = pkfma(splat2(wa.w), h2b[3], ab);
            aa = pkfma(splat2(wb.x), h2a[4], aa); ab = pkfma(splat2(wb.x), h2b[4], ab);
            aa = pkfma(splat2(wb.y), h2a[5], aa); ab = pkfma(splat2(wb.y), h2b[5], ab);
            aa = pkfma(splat2(wb.z), h2a[6], aa); ab = pkfma(splat2(wb.z), h2b[6], ab);
            aa = pkfma(splat2(wb.w), h2a[7], aa); ab = pkfma(splat2(wb.w), h2b[7], ab);

            f16x4 res;
            res.x = (_Float16)aa.x; res.y = (_Float16)aa.y;
            res.z = (_Float16)ab.x; res.w = (_Float16)ab.y;
            *(f16x4*)(&s_m[head][lr][c]) = res;
        }
    }

    __syncthreads();

    // ---------- Phase B: aligned_bilinear x2 + sigmoid (8 px/task) ----------
    // One task = 8 output px from one aligned 8B f16x4 read per source row
    // (2-way bank aliasing = free) + 1 guarded scalar left-neighbor.
    // sigmoid = rcp(1 + exp2(C*v)) with C = -log2(e) folded into the
    // y-interp (all x-interps are linear, so scaling commutes).
    float* out0 = out + (size_t)inst * (OH * OW) + (size_t)i0 * OW;
    float* out1 = out0 + (size_t)n_inst * (OH * OW);

    const float C = -1.44269504f;     // -log2(e)
    const int NU = OW / 8;            // 50 groups per output row
    const int ntaskb = TH * NU;       // 1250
    for (int t = tid; t < ntaskb; t += BLOCK) {
        const int row = t / NU;
        const int u   = t - row * NU;
        const int i   = i0 + row;
        const int ip  = (i > 0) ? (i - 1) : 0;
        const int y0  = ip >> 1;
        const float wy = (ip & 1) ? 0.5f : 0.0f;
        const int lr0 = y0 - r_begin;
        const int r1c = (y0 + 1 <= Hh - 1) ? (y0 + 1) : (Hh - 1);
        const int lr1 = r1c - r_begin;

        #pragma unroll
        for (int head = 0; head < 2; head++) {
            const f16x4 A0h = *(const f16x4*)(&s_m[head][lr0][4 * u]);
            const f16x4 A1h = *(const f16x4*)(&s_m[head][lr1][4 * u]);
            float p0 = 0.0f, p1 = 0.0f;
            if (u > 0) {
                p0 = (float)s_m[head][lr0][4 * u - 1];
                p1 = (float)s_m[head][lr1][4 * u - 1];
            }
            // y-interp, pre-scaled by C
            float Bv[4];
            #pragma unroll
            for (int m = 0; m < 4; m++) {
                const float a0 = (float)A0h[m], a1 = (float)A1h[m];
                Bv[m] = (a0 + (a1 - a0) * wy) * C;
            }
            const float PB = (p0 + (p1 - p0) * wy) * C;

            float e[8];
            e[0] = (u > 0) ? 0.5f * (PB + Bv[0]) : Bv[0];
            e[1] = Bv[0];
            e[2] = 0.5f * (Bv[0] + Bv[1]);
            e[3] = Bv[1];
            e[4] = 0.5f * (Bv[1] + Bv[2]);
            e[5] = Bv[2];
            e[6] = 0.5f * (Bv[2] + Bv[3]);
            e[7] = Bv[3];

            f32x4 lo, hi;
            #pragma unroll
            for (int k = 0; k < 4; k++) {
                lo[k] = __builtin_amdgcn_rcpf(1.0f + __builtin_amdgcn_exp2f(e[k]));
                hi[k] = __builtin_amdgcn_rcpf(1.0f + __builtin_amdgcn_exp2f(e[4 + k]));
            }

            float* dst = (head ? out1 : out0) + row * OW + 8 * u;
            __builtin_nontemporal_store(lo, (f32x4*)dst);
            __builtin_nontemporal_store(hi, (f32x4*)(dst + 4));
        }
    }
}

extern "C" void kernel_launch(void* const* d_in, const int* in_sizes, int n_in,
                              void* d_out, int out_size, void* d_ws, size_t ws_size,
                              hipStream_t stream) {
    const float* mask_feats = (const float*)d_in[0];
    const float* mparams    = (const float*)d_in[1];
    const float* bparams    = (const float*)d_in[2];
    const float* ilocs      = (const float*)d_in[3];
    const int*   im_inds    = (const int*)d_in[4];
    const int*   fpn_levels = (const int*)d_in[5];
    const int*   stride_p   = (const int*)d_in[6];
    float* out = (float*)d_out;

    const int n_inst = in_sizes[1] / NP;      // 128
    dim3 grid(OH / TH, n_inst);               // (16, 128)
    dim3 block(BLOCK);
    hipLaunchKernelGGL(dmh_fused, grid, block, 0, stream,
                       mask_feats, mparams, bparams, ilocs,
                       im_inds, fpn_levels, stride_p, out, n_inst);
}